// Round 1
// baseline (158.733 us; speedup 1.0000x reference)
//
#include <hip/hip_runtime.h>

// FullyConnectedTP: e3nn-style fully-connected tensor product, MUL=16.
// out[n, j] for j<16       = PW0 * sum_u ( w1[n,u,j]*u0[u]*v0 + w4[n,u,j]*d4[u]*inv3 )
// out[n, 16+w*3+k]         = PW1 * sum_u ( w2[n,u,w]*u0[u]*v1[k]*inv3 + w3[n,u,w]*u1[u,k]*v0*inv3 )
// where d4[u] = dot(u1[u,:], v1), weight reshaped (N,4,16,16) row-major.
//
// One wave per edge, lane = output element. Weight columns are read via
// wave-wide dword loads (rows are contiguous 64B) -> perfectly coalesced,
// each weight byte fetched once. Per-edge coefficients staged in LDS.

#define WAVE 64

__global__ __launch_bounds__(256) void fctp_kernel(
    const float* __restrict__ u,
    const float* __restrict__ v,
    const float* __restrict__ wgt,
    float* __restrict__ out,
    int N)
{
    constexpr float INV_SQRT3 = 0.57735026918962576451f; // 1/sqrt(3)
    constexpr float PW0 = 0.17677669529663688110f;       // sqrt(1/32)
    constexpr float PW1 = 0.30618621784789726f;          // sqrt(3/32)

    const int lane = threadIdx.x & 63;
    const int wv   = threadIdx.x >> 6;      // wave within block (0..3)
    int n = blockIdx.x * 4 + wv;
    if (n >= N) n = N - 1;                  // tail waves redo last edge (benign, deterministic)

    // per-wave LDS: [0..63] = u row, [64..79] = d4[u], [80..83] = v row
    __shared__ float sh[4][84];
    float* s = sh[wv];

    // ---- stage u and v (coalesced) ----
    s[lane] = u[(size_t)n * 64 + lane];
    if (lane < 4) s[80 + lane] = v[(size_t)n * 4 + lane];
    __syncthreads();

    // ---- d4[u] = dot(u1[u,:], v1) computed by lanes 0..15 ----
    if (lane < 16) {
        const int b = 16 + 3 * lane;
        float d = s[b] * s[81] + s[b + 1] * s[82] + s[b + 2] * s[83];
        s[64 + lane] = d;
    }
    __syncthreads();

    // ---- per-lane constants ----
    const bool is0 = (lane < 16);
    const int  o    = lane - 16;            // 0..47 for the l=1 outputs
    const int  wcol = is0 ? lane : (o / 3); // weight column this lane consumes
    const int  k    = is0 ? 0    : (o - 3 * wcol);
    const float v0  = s[80];
    const float p   = is0 ? v0        : s[81 + k] * INV_SQRT3;
    const float q   = is0 ? INV_SQRT3 : v0 * INV_SQRT3;
    // weight element offsets within this edge's 1024-float block:
    //   w1 @ 0, w2 @ 256, w3 @ 512, w4 @ 768 ; element [u][col] at u*16+col
    const int offA = is0 ? wcol         : (256 + wcol); // w1 : w2
    const int offB = is0 ? (768 + wcol) : (512 + wcol); // w4 : w3
    // LDS offset for the per-u "Y" coefficient: d4[u] vs u1[u][k]
    const int offY  = is0 ? 64 : (16 + k);
    const int ystep = is0 ? 1 : 3;

    const float* wp = wgt + (size_t)n * 1024;

    float acc = 0.0f;
#pragma unroll
    for (int uu = 0; uu < 16; ++uu) {
        const float X  = s[uu];                 // u0[u]  (LDS broadcast)
        const float Y  = s[offY + uu * ystep];  // d4[u] or u1[u][k]
        const float wa = wp[offA + uu * 16];    // column read, coalesced across wave
        const float wb = wp[offB + uu * 16];
        acc = fmaf(wa, X * p, acc);
        acc = fmaf(wb, Y * q, acc);
    }

    out[(size_t)n * 64 + lane] = (is0 ? PW0 : PW1) * acc;
}

extern "C" void kernel_launch(void* const* d_in, const int* in_sizes, int n_in,
                              void* d_out, int out_size, void* d_ws, size_t ws_size,
                              hipStream_t stream)
{
    const float* u   = (const float*)d_in[0];
    const float* v   = (const float*)d_in[1];
    const float* wgt = (const float*)d_in[2];
    float* out = (float*)d_out;

    const int N = in_sizes[1] / 4;      // v is (N,4)
    const int blocks = (N + 3) / 4;     // 4 edges (waves) per 256-thread block
    fctp_kernel<<<blocks, 256, 0, stream>>>(u, v, wgt, out, N);
}